// Round 7
// baseline (126.681 us; speedup 1.0000x reference)
//
#include <hip/hip_runtime.h>
#include <hip/hip_bf16.h>

// 2D DCT-II (4096x4096 fp32).  Round 6: WAVE-PER-FFT four-step.
// 4096 = 64x64: lane s holds 64 elems in VGPRs; in-register FFT64 (radix-4
// DIT, lane-uniform twiddles), mid twiddle e^{-2pi i s q/4096} (chained),
// ONE rotation-swizzled LDS 64x64 transpose, FFT64 again, conj-split via
// shfl (lane q <-> (64-q)&63), expk twiddle, coalesced stores.
// 2 real rows packed per complex FFT (z = rowA + i rowB).  One barrier per
// kernel, zero cross-wave dependencies, 5 independent waves/CU (32KB LDS).
// Plan: dct2(x->out) ; transpose(out->ws) ; dct2(ws->ws) ; transpose(ws->out).

#define L 4096

__device__ __forceinline__ float2 cmul(float2 a, float2 b) {
    return make_float2(a.x * b.x - a.y * b.y, a.x * b.y + a.y * b.x);
}

// radix-4 DIT butterfly (twiddles pre-applied), e^{-2pi i/N} convention
__device__ __forceinline__ void bfly4(float2& x0, float2& x1, float2& x2, float2& x3) {
    float t0x = x0.x + x2.x, t0y = x0.y + x2.y;
    float t1x = x0.x - x2.x, t1y = x0.y - x2.y;
    float t2x = x1.x + x3.x, t2y = x1.y + x3.y;
    float t3x = x1.x - x3.x, t3y = x1.y - x3.y;
    x0 = make_float2(t0x + t2x, t0y + t2y);
    x1 = make_float2(t1x + t3y, t1y - t3x);   // t1 + (-i)*t3
    x2 = make_float2(t0x - t2x, t0y - t2y);
    x3 = make_float2(t1x - t3y, t1y + t3x);   // t1 + (+i)*t3
}

// In-register 64-point DFT (natural in -> natural out), radix-4 DIT.
// Same stage structure as the verified R3-R6 LDS loop, L=64.
__device__ __forceinline__ void fft64(float2* z) {
    float2 t[64];
#pragma unroll
    for (int i = 0; i < 64; ++i)
        t[i] = z[((i & 3) << 4) | (i & 12) | ((i >> 4) & 3)];   // base-4 digit rev
    // stage 0: Q=1
#pragma unroll
    for (int g = 0; g < 16; ++g)
        bfly4(t[4*g+0], t[4*g+1], t[4*g+2], t[4*g+3]);
    // stage 1: Q=4, base = 16g + j, twiddle e^{-2pi i j/16}
#pragma unroll
    for (int j = 0; j < 4; ++j) {
        float2 w1, w2, w3;
        if (j != 0) {
            float c, s;
            __sincosf((float)j * -0.39269908169872414f, &s, &c);
            w1 = make_float2(c, s); w2 = cmul(w1, w1); w3 = cmul(w2, w1);
        }
#pragma unroll
        for (int g = 0; g < 4; ++g) {
            int b = 16*g + j;
            if (j != 0) {
                t[b+4]  = cmul(t[b+4],  w1);
                t[b+8]  = cmul(t[b+8],  w2);
                t[b+12] = cmul(t[b+12], w3);
            }
            bfly4(t[b], t[b+4], t[b+8], t[b+12]);
        }
    }
    // stage 2: Q=16, elems j,j+16,j+32,j+48, twiddle e^{-2pi i j/64}
#pragma unroll
    for (int j = 0; j < 16; ++j) {
        if (j != 0) {
            float c, s;
            __sincosf((float)j * -0.09817477042468103f, &s, &c);
            float2 w1 = make_float2(c, s);
            float2 w2 = cmul(w1, w1);
            float2 w3 = cmul(w2, w1);
            t[j+16] = cmul(t[j+16], w1);
            t[j+32] = cmul(t[j+32], w2);
            t[j+48] = cmul(t[j+48], w3);
        }
        bfly4(t[j], t[j+16], t[j+32], t[j+48]);
    }
#pragma unroll
    for (int i = 0; i < 64; ++i) z[i] = t[i];
}

__global__ __launch_bounds__(64)
void dct_wave_kernel(const float* __restrict__ in, float* __restrict__ out) {
    __shared__ float2 xch[L];            // 32 KB -> 5 waves/CU
    const int s = threadIdx.x;           // lane 0..63
    const int r0 = blockIdx.x * 2;
    const float* rowA = in + (size_t)r0 * L;
    const float* rowB = rowA + L;

    float2 z[64];

    // Makhoul reorder, packed load: v[n]=x[2n] (n<2048) else x[8191-2n].
    // Element (r,s) = v[64r+s].  float2 at x[128r+2s] gives v[64r+s] (.x)
    // and v[64(63-r)+(63-s)] (.y -> shfl from lane 63-s gives our z[63-r]).
#pragma unroll
    for (int r = 0; r < 32; ++r) {
        float2 fa = *reinterpret_cast<const float2*>(&rowA[128*r + 2*s]);
        float2 fb = *reinterpret_cast<const float2*>(&rowB[128*r + 2*s]);
        z[r] = make_float2(fa.x, fb.x);
        float ay = __shfl(fa.y, 63 - s);
        float by = __shfl(fb.y, 63 - s);
        z[63 - r] = make_float2(ay, by);
    }

    // Step 1: FFT64 over r (lane-local)
    fft64(z);

    // Step 2: mid twiddle z[q] *= e^{-2pi i s q/4096}, anchors every 8
    {
        const float ang = (float)s * -1.5339807878856412e-3f;   // -2pi s/4096
        float2 a1; __sincosf(ang, &a1.y, &a1.x);
#pragma unroll
        for (int q0 = 0; q0 < 64; q0 += 8) {
            float2 w;
            if (q0 == 0) w = make_float2(1.0f, 0.0f);
            else         __sincosf(ang * (float)q0, &w.y, &w.x);
#pragma unroll
            for (int d = 0; d < 8; ++d) {
                int q = q0 + d;
                if (q != 0) z[q] = cmul(z[q], w);
                if (d < 7) w = cmul(w, a1);
            }
        }
    }

    // Step 3: 64x64 transpose through LDS, rotation swizzle (4-cyc minimum
    // bank usage on both sides).  lds[q*64 + ((q+s)&63)] = H[q] from lane s.
#pragma unroll
    for (int q = 0; q < 64; ++q)
        xch[(q << 6) | ((q + s) & 63)] = z[q];
    __syncthreads();
#pragma unroll
    for (int i = 0; i < 64; ++i)
        z[i] = xch[(s << 6) | ((s + i) & 63)];

    // Step 4: FFT64 over s -> lane q=s holds X[q + 64p] in z[p]
    fft64(z);

    // Epilogue: conj-split + expk.  k = 64p + s; partner m=(4096-k)&4095 is
    // lane (64-s)&63, reg 63-p  (lane 0: own reg (64-p)&63).
    float* outA = out + (size_t)r0 * L;
    float* outB = outA + L;
    const int srcl = (64 - s) & 63;
    const float2 M = make_float2(0.99969881869620425f, 0.024541228522912288f); // e^{i pi/128}
    float2 w;
#pragma unroll
    for (int p = 0; p < 64; ++p) {
        if ((p & 15) == 0)   // anchor every 16 to bound chain error
            __sincosf((float)(s + 64*p) * 3.8349519697141029e-4f, &w.y, &w.x);
        float2 Zk = z[p];
        float2 Zm = make_float2(__shfl(z[63 - p].x, srcl),
                                __shfl(z[63 - p].y, srcl));
        if (s == 0) Zm = z[(64 - p) & 63];
        float vax = 0.5f * (Zk.x + Zm.x), vay = 0.5f * (Zk.y - Zm.y);
        float vbx = 0.5f * (Zk.y + Zm.y), vby = 0.5f * (Zm.x - Zk.x);
        outA[64*p + s] = vax * w.x + vay * w.y;
        outB[64*p + s] = vbx * w.x + vby * w.y;
        w = cmul(w, M);
    }
}

__global__ __launch_bounds__(256)
void transpose_kernel(const float* __restrict__ in, float* __restrict__ out) {
    // 64x64 tile, float4 global loads/stores, conflict-free LDS.
    __shared__ float tile[64][65];
    const int bx = blockIdx.x, by = blockIdx.y;
    const int tx = threadIdx.x & 15;
    const int ty = threadIdx.x >> 4;

#pragma unroll
    for (int i = 0; i < 4; ++i) {
        int r = ty + 16 * i;
        float4 f = *reinterpret_cast<const float4*>(
            &in[(size_t)(by * 64 + r) * L + bx * 64 + tx * 4]);
        tile[r][tx * 4 + 0] = f.x;
        tile[r][tx * 4 + 1] = f.y;
        tile[r][tx * 4 + 2] = f.z;
        tile[r][tx * 4 + 3] = f.w;
    }
    __syncthreads();
#pragma unroll
    for (int i = 0; i < 4; ++i) {
        int r = ty + 16 * i;
        float4 g = make_float4(tile[tx * 4 + 0][r], tile[tx * 4 + 1][r],
                               tile[tx * 4 + 2][r], tile[tx * 4 + 3][r]);
        *reinterpret_cast<float4*>(
            &out[(size_t)(bx * 64 + r) * L + by * 64 + tx * 4]) = g;
    }
}

extern "C" void kernel_launch(void* const* d_in, const int* in_sizes, int n_in,
                              void* d_out, int out_size, void* d_ws, size_t ws_size,
                              hipStream_t stream) {
    const float* x = (const float*)d_in[0];
    float* out = (float*)d_out;
    float* ws  = (float*)d_ws;   // needs 64 MB

    dim3 tgrid(L / 64, L / 64);

    dct_wave_kernel<<<L / 2, 64, 0, stream>>>(x, out);
    transpose_kernel<<<tgrid, 256, 0, stream>>>(out, ws);
    dct_wave_kernel<<<L / 2, 64, 0, stream>>>(ws, ws);
    transpose_kernel<<<tgrid, 256, 0, stream>>>(ws, out);
}